// Round 9
// baseline (197.304 us; speedup 1.0000x reference)
//
#include <hip/hip_runtime.h>

typedef unsigned short u16;
typedef unsigned int u32;
typedef __bf16 bf16x8 __attribute__((ext_vector_type(8)));
typedef short s16x4 __attribute__((ext_vector_type(4)));
typedef float f32x4 __attribute__((ext_vector_type(4)));

#define CC 768
#define TT 2560
#define NH 12
#define HD 64
#define KDIM 768

// 1/sqrt(64) * log2(e) -- folded into q in the QKV GEMM epilogue
#define QSCALE 0.18033688011112042f

__device__ __forceinline__ u16 f2bf(float f) {
  u32 u = __builtin_bit_cast(u32, f);
  u32 r = u + 0x7fffu + ((u >> 16) & 1u);
  return (u16)(r >> 16);
}

#if __has_builtin(__builtin_amdgcn_mfma_f32_16x16x16bf16_1k)
__device__ __forceinline__ f32x4 mfma16b(s16x4 a, s16x4 b, f32x4 c) {
  return __builtin_amdgcn_mfma_f32_16x16x16bf16_1k(a, b, c, 0, 0, 0);
}
#else
__device__ __forceinline__ f32x4 mfma16b(s16x4 a, s16x4 b, f32x4 c) {
  f32x4 d;
  asm("v_mfma_f32_16x16x16_bf16 %0, %1, %2, %3\n\ts_nop 7\n\ts_nop 7"
      : "=v"(d) : "v"(a), "v"(b), "v"(c));
  return d;
}
#endif

// ---------------- fused fp32 -> bf16 converts (1 launch) ----------------
__global__ void convall(const float* __restrict__ x,
                        const float* __restrict__ Wq, const float* __restrict__ Wk,
                        const float* __restrict__ Wv, const float* __restrict__ Wp,
                        u16* __restrict__ xb, u16* __restrict__ wqb, u16* __restrict__ wkb,
                        u16* __restrict__ wvb, u16* __restrict__ wpb,
                        int nx4, int nw4) {
  int z = blockIdx.y;
  const float* in; u16* out; int n4;
  switch (z) {
    case 0: in = x;  out = xb;  n4 = nx4; break;
    case 1: in = Wq; out = wqb; n4 = nw4; break;
    case 2: in = Wk; out = wkb; n4 = nw4; break;
    case 3: in = Wv; out = wvb; n4 = nw4; break;
    default: in = Wp; out = wpb; n4 = nw4; break;
  }
  int i = blockIdx.x * blockDim.x + threadIdx.x;
  if (i >= n4) return;
  float4 v = ((const float4*)in)[i];
  ushort4 o;
  o.x = f2bf(v.x); o.y = f2bf(v.y); o.z = f2bf(v.z); o.w = f2bf(v.w);
  ((ushort4*)out)[i] = o;
}

// ---------------- QKV projection GEMM ----------------
// z=0 -> q*QSCALE [B,H,T,64]   (transposed acc: vectorized ushort4 stores)
// z=1 -> k grouped [B,H, T/16, 2(kc), 16(key%16), 32(d%32)]  (transposed acc)
// z=2 -> v grouped [B,H, T/16, 64(d), 16(key%16)]            (normal acc)
__global__ __launch_bounds__(256) void gemm_qkv(
    const u16* __restrict__ xb,
    const u16* __restrict__ wqb, const u16* __restrict__ wkb, const u16* __restrict__ wvb,
    const float* __restrict__ bq, const float* __restrict__ bk, const float* __restrict__ bv,
    u16* __restrict__ qo, u16* __restrict__ ko, u16* __restrict__ vo)
{
  __shared__ __align__(16) u16 lds_a[128 * 72];
  __shared__ __align__(16) u16 lds_b[128 * 72];
  int z = blockIdx.z;
  const u16* W = (z == 0) ? wqb : (z == 1 ? wkb : wvb);
  const float* bias = (z == 0) ? bq : (z == 1 ? bk : bv);
  int n0 = blockIdx.x * 128;
  int m0 = blockIdx.y * 128;
  int tid = threadIdx.x;
  int lane = tid & 63, wv_ = tid >> 6;
  int wm = wv_ & 1, wn = wv_ >> 1;
  int mcol = lane & 15, quad = lane >> 4;
  int chunk = tid & 7, rbase = tid >> 3;

  f32x4 acc[4][4] = {};

  for (int k0 = 0; k0 < KDIM; k0 += 64) {
    __syncthreads();
#pragma unroll
    for (int r = 0; r < 4; ++r) {
      int row = rbase + r * 32;
      *(uint4*)&lds_a[row * 72 + chunk * 8] =
          *(const uint4*)&xb[(size_t)(m0 + row) * KDIM + k0 + chunk * 8];
      *(uint4*)&lds_b[row * 72 + chunk * 8] =
          *(const uint4*)&W[(size_t)(n0 + row) * KDIM + k0 + chunk * 8];
    }
    __syncthreads();
#pragma unroll
    for (int kc = 0; kc < 2; ++kc) {
      bf16x8 af[4], bfr[4];
#pragma unroll
      for (int i = 0; i < 4; i++)
        af[i] = *(const bf16x8*)&lds_a[(wm * 64 + i * 16 + mcol) * 72 + kc * 32 + quad * 8];
#pragma unroll
      for (int i = 0; i < 4; i++)
        bfr[i] = *(const bf16x8*)&lds_b[(wn * 64 + i * 16 + mcol) * 72 + kc * 32 + quad * 8];
      if (z == 2) {
#pragma unroll
        for (int i = 0; i < 4; i++)
#pragma unroll
          for (int j = 0; j < 4; j++)
            acc[i][j] = __builtin_amdgcn_mfma_f32_16x16x32_bf16(af[i], bfr[j], acc[i][j], 0, 0, 0);
      } else {
        // transposed: m-dim = W channel, n-dim = token
#pragma unroll
        for (int i = 0; i < 4; i++)
#pragma unroll
          for (int j = 0; j < 4; j++)
            acc[i][j] = __builtin_amdgcn_mfma_f32_16x16x32_bf16(bfr[j], af[i], acc[i][j], 0, 0, 0);
      }
    }
  }

  if (z == 2) {
    // normal orientation: lane holds 4 consecutive tokens, fixed channel
#pragma unroll
    for (int i = 0; i < 4; i++) {
      int rowb = m0 + wm * 64 + i * 16 + quad * 4;
      int b = rowb / TT;
      int tt0 = rowb - b * TT;     // key token, multiple of 4
#pragma unroll
      for (int j = 0; j < 4; j++) {
        int col = n0 + wn * 64 + j * 16 + mcol;
        int h = col >> 6, d = col & 63;
        float bb_ = bias[col];
        size_t bhoff = (size_t)(b * NH + h) * (TT * HD);
        ushort4 pk;
        pk.x = f2bf(acc[i][j][0] + bb_);
        pk.y = f2bf(acc[i][j][1] + bb_);
        pk.z = f2bf(acc[i][j][2] + bb_);
        pk.w = f2bf(acc[i][j][3] + bb_);
        *(ushort4*)&vo[bhoff + (size_t)(tt0 >> 4) * 1024 + d * 16 + (tt0 & 15)] = pk;
      }
    }
  } else {
    // transposed: lane holds 4 consecutive channels, fixed token
    u16* dst = (z == 0) ? qo : ko;
    float scale = (z == 0) ? QSCALE : 1.0f;
#pragma unroll
    for (int i = 0; i < 4; i++) {
      int token = m0 + wm * 64 + i * 16 + mcol;
      int b = token / TT;
      int tt = token - b * TT;
#pragma unroll
      for (int j = 0; j < 4; j++) {
        int ch0 = n0 + wn * 64 + j * 16 + quad * 4;
        int h = ch0 >> 6, d4 = ch0 & 63;
        float4 bb4 = *(const float4*)&bias[ch0];
        size_t bhoff = (size_t)(b * NH + h) * (TT * HD);
        ushort4 pk;
        pk.x = f2bf((acc[i][j][0] + bb4.x) * scale);
        pk.y = f2bf((acc[i][j][1] + bb4.y) * scale);
        pk.z = f2bf((acc[i][j][2] + bb4.z) * scale);
        pk.w = f2bf((acc[i][j][3] + bb4.w) * scale);
        if (z == 0) {
          *(ushort4*)&dst[bhoff + (size_t)tt * HD + d4] = pk;
        } else {
          *(ushort4*)&dst[bhoff + (size_t)(tt >> 4) * 1024 + (d4 >> 5) * 512 +
                          (tt & 15) * 32 + (d4 & 31)] = pk;
        }
      }
    }
  }
}

// ------- fused masked attention: 4 strips/wave, 4-way K-split per block ------
// 960 blocks x 256 thr (4 waves). All waves own the SAME 4 q-strips (shared
// load pattern, ILP=4 preserved); wave w processes kt in [5w, 5w+5) -- no load
// duplication (disjoint kt ranges). Partials additive (m=0): waves 1..3 dump
// O/rsum to LDS, one barrier, wave 0 sums + stores.
struct Strip {
  bf16x8 qf0, qf1;
  f32x4 o0, o1, o2, o3;
  f32x4 racc;   // ones-row MFMA accumulator: racc[0] = softmax denominator
};

__device__ __forceinline__ void strip_step(
    Strip& S, bf16x8 kf0, bf16x8 kf1,
    s16x4 vf0, s16x4 vf1, s16x4 vf2, s16x4 vf3,
    bool maskg, int mcol, int quad)
{
  f32x4 st = {0.f, 0.f, 0.f, 0.f};
  st = __builtin_amdgcn_mfma_f32_16x16x32_bf16(kf0, S.qf0, st, 0, 0, 0);
  st = __builtin_amdgcn_mfma_f32_16x16x32_bf16(kf1, S.qf1, st, 0, 0, 0);
  float p0 = __builtin_amdgcn_exp2f(st[0]);
  float p1 = __builtin_amdgcn_exp2f(st[1]);
  float p2 = __builtin_amdgcn_exp2f(st[2]);
  float p3 = __builtin_amdgcn_exp2f(st[3]);
  if (maskg) {
    int j0 = quad * 4;
    p0 = (j0 + 0 > mcol) ? 0.f : p0;
    p1 = (j0 + 1 > mcol) ? 0.f : p1;
    p2 = (j0 + 2 > mcol) ? 0.f : p2;
    p3 = (j0 + 3 > mcol) ? 0.f : p3;
  }
  u32 b0 = __builtin_bit_cast(u32, p0) + 0x8000u;
  u32 b1 = __builtin_bit_cast(u32, p1) + 0x8000u;
  u32 b2 = __builtin_bit_cast(u32, p2) + 0x8000u;
  u32 b3 = __builtin_bit_cast(u32, p3) + 0x8000u;
  uint2 pk;
  pk.x = __builtin_amdgcn_perm(b1, b0, 0x07060302u);
  pk.y = __builtin_amdgcn_perm(b3, b2, 0x07060302u);
  s16x4 pf = __builtin_bit_cast(s16x4, pk);
  const s16x4 ones = {0x3F80, 0x3F80, 0x3F80, 0x3F80};  // bf16 1.0 x4
  S.racc = mfma16b(ones, pf, S.racc);
  S.o0 = mfma16b(vf0, pf, S.o0);
  S.o1 = mfma16b(vf1, pf, S.o1);
  S.o2 = mfma16b(vf2, pf, S.o2);
  S.o3 = mfma16b(vf3, pf, S.o3);
}

#define OSTR 68   // padded f32 row stride for combine staging (bank stagger)

__global__ __launch_bounds__(256) void attn(
    const u16* __restrict__ q, const u16* __restrict__ kg,
    const u16* __restrict__ vg, u16* __restrict__ y)
{
  __shared__ float lds_o[3][4][16 * OSTR];
  __shared__ float lds_r[3][64];

  int tid = threadIdx.x;
  int lane = tid & 63, w = tid >> 6;   // w = K-quarter owner
  int mcol = lane & 15, quad = lane >> 4;
  int gid = blockIdx.x;
  int c = gid & 7;              // XCD (round-robin dispatch heuristic)
  int idx = gid >> 3;           // 0..119
  int sub = idx / 40;           // 0..2  -> 3 bh per XCD (K/V resident in L2)
  int s = idx - sub * 40;       // 0..39
  int bh = c * 3 + sub;
  int hb = s >> 3;              // 0..4  (512-row span)
  int r = s & 7;                // light local strip; heavy local = 7-r
  int b = bh / NH, h = bh - b * NH;
  const u16* qp = q + (size_t)bh * TT * HD;
  const u16* kp = kg + (size_t)bh * TT * HD;
  const u16* vp = vg + (size_t)bh * TT * HD;

  int base = hb * 512;
  int rh = 7 - r;
  int qr[4];
  qr[0] = base + r * 16;              // L1 (half 0 of 256-tile)
  qr[1] = base + 128 + rh * 16;       // H1 (half 1)
  qr[2] = base + 256 + r * 16;        // L2
  qr[3] = base + 384 + rh * 16;       // H2

  Strip S[4];
#pragma unroll
  for (int i = 0; i < 4; ++i) {
    S[i].qf0 = *(const bf16x8*)&qp[(size_t)(qr[i] + mcol) * HD + quad * 8];
    S[i].qf1 = *(const bf16x8*)&qp[(size_t)(qr[i] + mcol) * HD + 32 + quad * 8];
    S[i].o0 = {0.f, 0.f, 0.f, 0.f};
    S[i].o1 = {0.f, 0.f, 0.f, 0.f};
    S[i].o2 = {0.f, 0.f, 0.f, 0.f};
    S[i].o3 = {0.f, 0.f, 0.f, 0.f};
    S[i].racc = {0.f, 0.f, 0.f, 0.f};
  }

  int koff = mcol * 32 + quad * 8;  // u16 offset in K group (b128, coalesced)
  int voff = mcol * 16 + quad * 4;  // u16 offset in V df-slab (b64, coalesced)

  for (int kt = w * 5; kt < w * 5 + 5; ++kt) {
    const u16* ktb = kp + kt * (128 * HD);
    const u16* vtb = vp + kt * (128 * HD);
    if ((kt & 1) == 0) {
      // even tile: heavy strips full 8 groups; light strips groups 0..r
#pragma unroll
      for (int g = 0; g < 8; ++g) {
        bf16x8 kf0 = *(const bf16x8*)&ktb[g * 1024 + koff];
        bf16x8 kf1 = *(const bf16x8*)&ktb[g * 1024 + 512 + koff];
        s16x4 vf0 = *(const s16x4*)&vtb[g * 1024 + 0 * 256 + voff];
        s16x4 vf1 = *(const s16x4*)&vtb[g * 1024 + 1 * 256 + voff];
        s16x4 vf2 = *(const s16x4*)&vtb[g * 1024 + 2 * 256 + voff];
        s16x4 vf3 = *(const s16x4*)&vtb[g * 1024 + 3 * 256 + voff];
        strip_step(S[1], kf0, kf1, vf0, vf1, vf2, vf3, false, mcol, quad);
        strip_step(S[3], kf0, kf1, vf0, vf1, vf2, vf3, false, mcol, quad);
        if (g <= r) {
          bool mg = (g == r);
          strip_step(S[0], kf0, kf1, vf0, vf1, vf2, vf3, mg, mcol, quad);
          strip_step(S[2], kf0, kf1, vf0, vf1, vf2, vf3, mg, mcol, quad);
        }
      }
    } else {
      // odd tile: heavy strips groups 0..rh (partial at rh); light strips skip
      for (int g = 0; g <= rh; ++g) {
        bf16x8 kf0 = *(const bf16x8*)&ktb[g * 1024 + koff];
        bf16x8 kf1 = *(const bf16x8*)&ktb[g * 1024 + 512 + koff];
        s16x4 vf0 = *(const s16x4*)&vtb[g * 1024 + 0 * 256 + voff];
        s16x4 vf1 = *(const s16x4*)&vtb[g * 1024 + 1 * 256 + voff];
        s16x4 vf2 = *(const s16x4*)&vtb[g * 1024 + 2 * 256 + voff];
        s16x4 vf3 = *(const s16x4*)&vtb[g * 1024 + 3 * 256 + voff];
        bool mg = (g == rh);
        strip_step(S[1], kf0, kf1, vf0, vf1, vf2, vf3, mg, mcol, quad);
        strip_step(S[3], kf0, kf1, vf0, vf1, vf2, vf3, mg, mcol, quad);
      }
    }
  }

  // ---- combine the four K-quarters through LDS (partials additive, m=0) ----
  if (w > 0) {
#pragma unroll
    for (int i = 0; i < 4; ++i) {
      f32x4 oo[4] = {S[i].o0, S[i].o1, S[i].o2, S[i].o3};
#pragma unroll
      for (int df = 0; df < 4; ++df)
        *(f32x4*)&lds_o[w - 1][i][mcol * OSTR + df * 16 + quad * 4] = oo[df];
      if (quad == 0) lds_r[w - 1][i * 16 + mcol] = S[i].racc[0];
    }
  }
  __syncthreads();
  if (w == 0) {
#pragma unroll
    for (int i = 0; i < 4; ++i) {
      float denom = S[i].racc[0] + lds_r[0][i * 16 + mcol] +
                    lds_r[1][i * 16 + mcol] + lds_r[2][i * 16 + mcol];
      float inv = 1.0f / denom;
      f32x4 oo[4] = {S[i].o0, S[i].o1, S[i].o2, S[i].o3};
      size_t yrow = ((size_t)(b * TT + qr[i] + mcol)) * CC + h * HD;
#pragma unroll
      for (int df = 0; df < 4; ++df) {
        int lo = mcol * OSTR + df * 16 + quad * 4;
        f32x4 p0 = *(const f32x4*)&lds_o[0][i][lo];
        f32x4 p1 = *(const f32x4*)&lds_o[1][i][lo];
        f32x4 p2 = *(const f32x4*)&lds_o[2][i][lo];
        ushort4 pk;
        pk.x = f2bf((oo[df][0] + p0[0] + p1[0] + p2[0]) * inv);
        pk.y = f2bf((oo[df][1] + p0[1] + p1[1] + p2[1]) * inv);
        pk.z = f2bf((oo[df][2] + p0[2] + p1[2] + p2[2]) * inv);
        pk.w = f2bf((oo[df][3] + p0[3] + p1[3] + p2[3]) * inv);
        *(ushort4*)&y[yrow + df * 16 + quad * 4] = pk;
      }
    }
  }
}

// ---------------- output projection GEMM (transposed epilogue) ----------------
__global__ __launch_bounds__(256) void gemm_out(
    const u16* __restrict__ yb, const u16* __restrict__ wpb,
    const float* __restrict__ bp, float* __restrict__ out)
{
  __shared__ __align__(16) u16 lds_a[128 * 72];
  __shared__ __align__(16) u16 lds_b[128 * 72];
  int n0 = blockIdx.x * 128;
  int m0 = blockIdx.y * 128;
  int tid = threadIdx.x;
  int lane = tid & 63, wv_ = tid >> 6;
  int wm = wv_ & 1, wn = wv_ >> 1;
  int mcol = lane & 15, quad = lane >> 4;
  int chunk = tid & 7, rbase = tid >> 3;

  f32x4 acc[4][4] = {};

  for (int k0 = 0; k0 < KDIM; k0 += 64) {
    __syncthreads();
#pragma unroll
    for (int r = 0; r < 4; ++r) {
      int row = rbase + r * 32;
      *(uint4*)&lds_a[row * 72 + chunk * 8] =
          *(const uint4*)&yb[(size_t)(m0 + row) * KDIM + k0 + chunk * 8];
      *(uint4*)&lds_b[row * 72 + chunk * 8] =
          *(const uint4*)&wpb[(size_t)(n0 + row) * KDIM + k0 + chunk * 8];
    }
    __syncthreads();
#pragma unroll
    for (int kc = 0; kc < 2; ++kc) {
      bf16x8 af[4], bfr[4];
#pragma unroll
      for (int i = 0; i < 4; i++)
        af[i] = *(const bf16x8*)&lds_a[(wm * 64 + i * 16 + mcol) * 72 + kc * 32 + quad * 8];
#pragma unroll
      for (int i = 0; i < 4; i++)
        bfr[i] = *(const bf16x8*)&lds_b[(wn * 64 + i * 16 + mcol) * 72 + kc * 32 + quad * 8];
      // transposed: m-dim = channel (W row), n-dim = token
#pragma unroll
      for (int i = 0; i < 4; i++)
#pragma unroll
        for (int j = 0; j < 4; j++)
          acc[i][j] = __builtin_amdgcn_mfma_f32_16x16x32_bf16(bfr[j], af[i], acc[i][j], 0, 0, 0);
    }
  }

#pragma unroll
  for (int i = 0; i < 4; i++) {
    int token = m0 + wm * 64 + i * 16 + mcol;
#pragma unroll
    for (int j = 0; j < 4; j++) {
      int ch0 = n0 + wn * 64 + j * 16 + quad * 4;
      float4 bb4 = *(const float4*)&bp[ch0];
      float4 o4;
      o4.x = acc[i][j][0] + bb4.x;
      o4.y = acc[i][j][1] + bb4.y;
      o4.z = acc[i][j][2] + bb4.z;
      o4.w = acc[i][j][3] + bb4.w;
      *(float4*)&out[(size_t)token * CC + ch0] = o4;
    }
  }
}

extern "C" void kernel_launch(void* const* d_in, const int* in_sizes, int n_in,
                              void* d_out, int out_size, void* d_ws, size_t ws_size,
                              hipStream_t stream) {
  const float* x  = (const float*)d_in[0];
  const float* Wk = (const float*)d_in[1];
  const float* bk = (const float*)d_in[2];
  const float* Wq = (const float*)d_in[3];
  const float* bq = (const float*)d_in[4];
  const float* Wv = (const float*)d_in[5];
  const float* bv = (const float*)d_in[6];
  const float* Wp = (const float*)d_in[7];
  const float* bp = (const float*)d_in[8];
  float* out = (float*)d_out;

  char* ws = (char*)d_ws;
  size_t off = 0;
  auto alloc = [&](size_t bytes) {
    void* p = ws + off;
    off += (bytes + 255) & ~(size_t)255;
    return p;
  };
  const size_t NX = (size_t)2 * TT * CC;
  const size_t NW = (size_t)CC * CC;
  u16* xb  = (u16*)alloc(NX * 2);
  u16* wqb = (u16*)alloc(NW * 2);
  u16* wkb = (u16*)alloc(NW * 2);
  u16* wvb = (u16*)alloc(NW * 2);
  u16* wpb = (u16*)alloc(NW * 2);
  u16* qws = (u16*)alloc(NX * 2);
  u16* kws = (u16*)alloc(NX * 2);
  u16* vgw = (u16*)alloc(NX * 2);
  u16* yws = (u16*)alloc(NX * 2);

  int nx4 = (int)(NX / 4), nw4 = (int)(NW / 4);
  convall<<<dim3((nx4 + 255) / 256, 5), 256, 0, stream>>>(
      x, Wq, Wk, Wv, Wp, xb, wqb, wkb, wvb, wpb, nx4, nw4);

  gemm_qkv<<<dim3(6, 40, 3), 256, 0, stream>>>(xb, wqb, wkb, wvb, bq, bk, bv,
                                               qws, kws, vgw);
  attn<<<dim3(960), 256, 0, stream>>>(qws, kws, vgw, yws);
  gemm_out<<<dim3(6, 40), 256, 0, stream>>>(yws, wpb, bp, out);
}

// Round 10
// 188.822 us; speedup vs baseline: 1.0449x; 1.0449x over previous
//
#include <hip/hip_runtime.h>

typedef unsigned short u16;
typedef unsigned int u32;
typedef __bf16 bf16x8 __attribute__((ext_vector_type(8)));
typedef short s16x4 __attribute__((ext_vector_type(4)));
typedef float f32x4 __attribute__((ext_vector_type(4)));

#define CC 768
#define TT 2560
#define NH 12
#define HD 64
#define KDIM 768

// 1/sqrt(64) * log2(e) -- folded into q in the QKV GEMM epilogue
#define QSCALE 0.18033688011112042f

__device__ __forceinline__ u16 f2bf(float f) {
  u32 u = __builtin_bit_cast(u32, f);
  u32 r = u + 0x7fffu + ((u >> 16) & 1u);
  return (u16)(r >> 16);
}

#if __has_builtin(__builtin_amdgcn_mfma_f32_16x16x16bf16_1k)
__device__ __forceinline__ f32x4 mfma16b(s16x4 a, s16x4 b, f32x4 c) {
  return __builtin_amdgcn_mfma_f32_16x16x16bf16_1k(a, b, c, 0, 0, 0);
}
#else
__device__ __forceinline__ f32x4 mfma16b(s16x4 a, s16x4 b, f32x4 c) {
  f32x4 d;
  asm("v_mfma_f32_16x16x16_bf16 %0, %1, %2, %3\n\ts_nop 7\n\ts_nop 7"
      : "=v"(d) : "v"(a), "v"(b), "v"(c));
  return d;
}
#endif

// ---------------- fused fp32 -> bf16 converts (1 launch) ----------------
__global__ void convall(const float* __restrict__ x,
                        const float* __restrict__ Wq, const float* __restrict__ Wk,
                        const float* __restrict__ Wv, const float* __restrict__ Wp,
                        u16* __restrict__ xb, u16* __restrict__ wqb, u16* __restrict__ wkb,
                        u16* __restrict__ wvb, u16* __restrict__ wpb,
                        int nx4, int nw4) {
  int z = blockIdx.y;
  const float* in; u16* out; int n4;
  switch (z) {
    case 0: in = x;  out = xb;  n4 = nx4; break;
    case 1: in = Wq; out = wqb; n4 = nw4; break;
    case 2: in = Wk; out = wkb; n4 = nw4; break;
    case 3: in = Wv; out = wvb; n4 = nw4; break;
    default: in = Wp; out = wpb; n4 = nw4; break;
  }
  int i = blockIdx.x * blockDim.x + threadIdx.x;
  if (i >= n4) return;
  float4 v = ((const float4*)in)[i];
  ushort4 o;
  o.x = f2bf(v.x); o.y = f2bf(v.y); o.z = f2bf(v.z); o.w = f2bf(v.w);
  ((ushort4*)out)[i] = o;
}

// ---------------- QKV projection GEMM ----------------
// z=0 -> q*QSCALE [B,H,T,64]   (transposed acc: vectorized ushort4 stores)
// z=1 -> k grouped [B,H, T/16, 2(kc), 16(key%16), 32(d%32)]  (transposed acc)
// z=2 -> v grouped [B,H, T/16, 64(d), 16(key%16)]            (normal acc)
__global__ __launch_bounds__(256) void gemm_qkv(
    const u16* __restrict__ xb,
    const u16* __restrict__ wqb, const u16* __restrict__ wkb, const u16* __restrict__ wvb,
    const float* __restrict__ bq, const float* __restrict__ bk, const float* __restrict__ bv,
    u16* __restrict__ qo, u16* __restrict__ ko, u16* __restrict__ vo)
{
  __shared__ __align__(16) u16 lds_a[128 * 72];
  __shared__ __align__(16) u16 lds_b[128 * 72];
  int z = blockIdx.z;
  const u16* W = (z == 0) ? wqb : (z == 1 ? wkb : wvb);
  const float* bias = (z == 0) ? bq : (z == 1 ? bk : bv);
  int n0 = blockIdx.x * 128;
  int m0 = blockIdx.y * 128;
  int tid = threadIdx.x;
  int lane = tid & 63, wv_ = tid >> 6;
  int wm = wv_ & 1, wn = wv_ >> 1;
  int mcol = lane & 15, quad = lane >> 4;
  int chunk = tid & 7, rbase = tid >> 3;

  f32x4 acc[4][4] = {};

  for (int k0 = 0; k0 < KDIM; k0 += 64) {
    __syncthreads();
#pragma unroll
    for (int r = 0; r < 4; ++r) {
      int row = rbase + r * 32;
      *(uint4*)&lds_a[row * 72 + chunk * 8] =
          *(const uint4*)&xb[(size_t)(m0 + row) * KDIM + k0 + chunk * 8];
      *(uint4*)&lds_b[row * 72 + chunk * 8] =
          *(const uint4*)&W[(size_t)(n0 + row) * KDIM + k0 + chunk * 8];
    }
    __syncthreads();
#pragma unroll
    for (int kc = 0; kc < 2; ++kc) {
      bf16x8 af[4], bfr[4];
#pragma unroll
      for (int i = 0; i < 4; i++)
        af[i] = *(const bf16x8*)&lds_a[(wm * 64 + i * 16 + mcol) * 72 + kc * 32 + quad * 8];
#pragma unroll
      for (int i = 0; i < 4; i++)
        bfr[i] = *(const bf16x8*)&lds_b[(wn * 64 + i * 16 + mcol) * 72 + kc * 32 + quad * 8];
      if (z == 2) {
#pragma unroll
        for (int i = 0; i < 4; i++)
#pragma unroll
          for (int j = 0; j < 4; j++)
            acc[i][j] = __builtin_amdgcn_mfma_f32_16x16x32_bf16(af[i], bfr[j], acc[i][j], 0, 0, 0);
      } else {
        // transposed: m-dim = W channel, n-dim = token
#pragma unroll
        for (int i = 0; i < 4; i++)
#pragma unroll
          for (int j = 0; j < 4; j++)
            acc[i][j] = __builtin_amdgcn_mfma_f32_16x16x32_bf16(bfr[j], af[i], acc[i][j], 0, 0, 0);
      }
    }
  }

  if (z == 2) {
    // normal orientation: lane holds 4 consecutive tokens, fixed channel
#pragma unroll
    for (int i = 0; i < 4; i++) {
      int rowb = m0 + wm * 64 + i * 16 + quad * 4;
      int b = rowb / TT;
      int tt0 = rowb - b * TT;     // key token, multiple of 4
#pragma unroll
      for (int j = 0; j < 4; j++) {
        int col = n0 + wn * 64 + j * 16 + mcol;
        int h = col >> 6, d = col & 63;
        float bb_ = bias[col];
        size_t bhoff = (size_t)(b * NH + h) * (TT * HD);
        ushort4 pk;
        pk.x = f2bf(acc[i][j][0] + bb_);
        pk.y = f2bf(acc[i][j][1] + bb_);
        pk.z = f2bf(acc[i][j][2] + bb_);
        pk.w = f2bf(acc[i][j][3] + bb_);
        *(ushort4*)&vo[bhoff + (size_t)(tt0 >> 4) * 1024 + d * 16 + (tt0 & 15)] = pk;
      }
    }
  } else {
    // transposed: lane holds 4 consecutive channels, fixed token
    u16* dst = (z == 0) ? qo : ko;
    float scale = (z == 0) ? QSCALE : 1.0f;
#pragma unroll
    for (int i = 0; i < 4; i++) {
      int token = m0 + wm * 64 + i * 16 + mcol;
      int b = token / TT;
      int tt = token - b * TT;
#pragma unroll
      for (int j = 0; j < 4; j++) {
        int ch0 = n0 + wn * 64 + j * 16 + quad * 4;
        int h = ch0 >> 6, d4 = ch0 & 63;
        float4 bb4 = *(const float4*)&bias[ch0];
        size_t bhoff = (size_t)(b * NH + h) * (TT * HD);
        ushort4 pk;
        pk.x = f2bf((acc[i][j][0] + bb4.x) * scale);
        pk.y = f2bf((acc[i][j][1] + bb4.y) * scale);
        pk.z = f2bf((acc[i][j][2] + bb4.z) * scale);
        pk.w = f2bf((acc[i][j][3] + bb4.w) * scale);
        if (z == 0) {
          *(ushort4*)&dst[bhoff + (size_t)tt * HD + d4] = pk;
        } else {
          *(ushort4*)&dst[bhoff + (size_t)(tt >> 4) * 1024 + (d4 >> 5) * 512 +
                          (tt & 15) * 32 + (d4 & 31)] = pk;
        }
      }
    }
  }
}

// ------- fused masked attention: 4 strips/wave, 2-way K-split per block ------
// (round-5 structure, measured optimum; P-pack truncates -- bias cancels in
// O/rsum since rsum is computed from the same truncated pf via ones-MFMA)
struct Strip {
  bf16x8 qf0, qf1;
  f32x4 o0, o1, o2, o3;
  f32x4 racc;   // ones-row MFMA accumulator: racc[0] = softmax denominator
};

__device__ __forceinline__ void strip_step(
    Strip& S, bf16x8 kf0, bf16x8 kf1,
    s16x4 vf0, s16x4 vf1, s16x4 vf2, s16x4 vf3,
    bool maskg, int mcol, int quad)
{
  f32x4 st = {0.f, 0.f, 0.f, 0.f};
  st = __builtin_amdgcn_mfma_f32_16x16x32_bf16(kf0, S.qf0, st, 0, 0, 0);
  st = __builtin_amdgcn_mfma_f32_16x16x32_bf16(kf1, S.qf1, st, 0, 0, 0);
  float p0 = __builtin_amdgcn_exp2f(st[0]);
  float p1 = __builtin_amdgcn_exp2f(st[1]);
  float p2 = __builtin_amdgcn_exp2f(st[2]);
  float p3 = __builtin_amdgcn_exp2f(st[3]);
  if (maskg) {
    int j0 = quad * 4;
    p0 = (j0 + 0 > mcol) ? 0.f : p0;
    p1 = (j0 + 1 > mcol) ? 0.f : p1;
    p2 = (j0 + 2 > mcol) ? 0.f : p2;
    p3 = (j0 + 3 > mcol) ? 0.f : p3;
  }
  // truncate to bf16 (no rounding add): bias cancels against rsum
  uint2 pk;
  pk.x = __builtin_amdgcn_perm(__builtin_bit_cast(u32, p1),
                               __builtin_bit_cast(u32, p0), 0x07060302u);
  pk.y = __builtin_amdgcn_perm(__builtin_bit_cast(u32, p3),
                               __builtin_bit_cast(u32, p2), 0x07060302u);
  s16x4 pf = __builtin_bit_cast(s16x4, pk);
  const s16x4 ones = {0x3F80, 0x3F80, 0x3F80, 0x3F80};  // bf16 1.0 x4
  S.racc = mfma16b(ones, pf, S.racc);
  S.o0 = mfma16b(vf0, pf, S.o0);
  S.o1 = mfma16b(vf1, pf, S.o1);
  S.o2 = mfma16b(vf2, pf, S.o2);
  S.o3 = mfma16b(vf3, pf, S.o3);
}

#define OSTR 68   // padded f32 row stride for combine staging (bank stagger)

__global__ __launch_bounds__(128) void attn(
    const u16* __restrict__ q, const u16* __restrict__ kg,
    const u16* __restrict__ vg, u16* __restrict__ y)
{
  __shared__ float lds_o[4][16 * OSTR];
  __shared__ float lds_r[64];

  int tid = threadIdx.x;
  int lane = tid & 63, w = tid >> 6;   // w = K-half owner
  int mcol = lane & 15, quad = lane >> 4;
  int gid = blockIdx.x;
  int c = gid & 7;              // XCD (round-robin dispatch heuristic)
  int idx = gid >> 3;           // 0..119
  int sub = idx / 40;           // 0..2  -> 3 bh per XCD (K/V resident in L2)
  int s = idx - sub * 40;       // 0..39
  int bh = c * 3 + sub;
  int hb = s >> 3;              // 0..4  (512-row span)
  int r = s & 7;                // light local strip; heavy local = 7-r
  int b = bh / NH, h = bh - b * NH;
  const u16* qp = q + (size_t)bh * TT * HD;
  const u16* kp = kg + (size_t)bh * TT * HD;
  const u16* vp = vg + (size_t)bh * TT * HD;

  int base = hb * 512;
  int rh = 7 - r;
  int qr[4];
  qr[0] = base + r * 16;              // L1 (half 0 of 256-tile)
  qr[1] = base + 128 + rh * 16;       // H1 (half 1)
  qr[2] = base + 256 + r * 16;        // L2
  qr[3] = base + 384 + rh * 16;       // H2

  Strip S[4];
#pragma unroll
  for (int i = 0; i < 4; ++i) {
    S[i].qf0 = *(const bf16x8*)&qp[(size_t)(qr[i] + mcol) * HD + quad * 8];
    S[i].qf1 = *(const bf16x8*)&qp[(size_t)(qr[i] + mcol) * HD + 32 + quad * 8];
    S[i].o0 = {0.f, 0.f, 0.f, 0.f};
    S[i].o1 = {0.f, 0.f, 0.f, 0.f};
    S[i].o2 = {0.f, 0.f, 0.f, 0.f};
    S[i].o3 = {0.f, 0.f, 0.f, 0.f};
    S[i].racc = {0.f, 0.f, 0.f, 0.f};
  }

  int koff = mcol * 32 + quad * 8;  // u16 offset in K group (b128, coalesced)
  int voff = mcol * 16 + quad * 4;  // u16 offset in V df-slab (b64, coalesced)

  for (int kt = w * 10; kt < w * 10 + 10; ++kt) {
    const u16* ktb = kp + kt * (128 * HD);
    const u16* vtb = vp + kt * (128 * HD);
    if ((kt & 1) == 0) {
      // even tile: heavy strips full 8 groups; light strips groups 0..r
#pragma unroll
      for (int g = 0; g < 8; ++g) {
        bf16x8 kf0 = *(const bf16x8*)&ktb[g * 1024 + koff];
        bf16x8 kf1 = *(const bf16x8*)&ktb[g * 1024 + 512 + koff];
        s16x4 vf0 = *(const s16x4*)&vtb[g * 1024 + 0 * 256 + voff];
        s16x4 vf1 = *(const s16x4*)&vtb[g * 1024 + 1 * 256 + voff];
        s16x4 vf2 = *(const s16x4*)&vtb[g * 1024 + 2 * 256 + voff];
        s16x4 vf3 = *(const s16x4*)&vtb[g * 1024 + 3 * 256 + voff];
        strip_step(S[1], kf0, kf1, vf0, vf1, vf2, vf3, false, mcol, quad);
        strip_step(S[3], kf0, kf1, vf0, vf1, vf2, vf3, false, mcol, quad);
        if (g <= r) {
          bool mg = (g == r);
          strip_step(S[0], kf0, kf1, vf0, vf1, vf2, vf3, mg, mcol, quad);
          strip_step(S[2], kf0, kf1, vf0, vf1, vf2, vf3, mg, mcol, quad);
        }
      }
    } else {
      // odd tile: heavy strips groups 0..rh (partial at rh); light strips skip
      for (int g = 0; g <= rh; ++g) {
        bf16x8 kf0 = *(const bf16x8*)&ktb[g * 1024 + koff];
        bf16x8 kf1 = *(const bf16x8*)&ktb[g * 1024 + 512 + koff];
        s16x4 vf0 = *(const s16x4*)&vtb[g * 1024 + 0 * 256 + voff];
        s16x4 vf1 = *(const s16x4*)&vtb[g * 1024 + 1 * 256 + voff];
        s16x4 vf2 = *(const s16x4*)&vtb[g * 1024 + 2 * 256 + voff];
        s16x4 vf3 = *(const s16x4*)&vtb[g * 1024 + 3 * 256 + voff];
        bool mg = (g == rh);
        strip_step(S[1], kf0, kf1, vf0, vf1, vf2, vf3, mg, mcol, quad);
        strip_step(S[3], kf0, kf1, vf0, vf1, vf2, vf3, mg, mcol, quad);
      }
    }
  }

  // ---- combine the two K-halves through LDS (partials are additive, m=0) ----
  if (w == 1) {
#pragma unroll
    for (int i = 0; i < 4; ++i) {
      f32x4 oo[4] = {S[i].o0, S[i].o1, S[i].o2, S[i].o3};
#pragma unroll
      for (int df = 0; df < 4; ++df)
        *(f32x4*)&lds_o[i][mcol * OSTR + df * 16 + quad * 4] = oo[df];
      if (quad == 0) lds_r[i * 16 + mcol] = S[i].racc[0];
    }
  }
  __syncthreads();
  if (w == 0) {
#pragma unroll
    for (int i = 0; i < 4; ++i) {
      float denom = S[i].racc[0] + lds_r[i * 16 + mcol];
      float inv = 1.0f / denom;
      f32x4 oo[4] = {S[i].o0, S[i].o1, S[i].o2, S[i].o3};
      size_t yrow = ((size_t)(b * TT + qr[i] + mcol)) * CC + h * HD;
#pragma unroll
      for (int df = 0; df < 4; ++df) {
        f32x4 other = *(const f32x4*)&lds_o[i][mcol * OSTR + df * 16 + quad * 4];
        ushort4 pk;
        pk.x = f2bf((oo[df][0] + other[0]) * inv);
        pk.y = f2bf((oo[df][1] + other[1]) * inv);
        pk.z = f2bf((oo[df][2] + other[2]) * inv);
        pk.w = f2bf((oo[df][3] + other[3]) * inv);
        *(ushort4*)&y[yrow + df * 16 + quad * 4] = pk;
      }
    }
  }
}

// ------- output projection GEMM: 64x128 tile, 480 blocks (1.9/CU) -----------
// transposed epilogue: acc m-dim = channel, n-dim = token -> float4 stores
__global__ __launch_bounds__(256) void gemm_out(
    const u16* __restrict__ yb, const u16* __restrict__ wpb,
    const float* __restrict__ bp, float* __restrict__ out)
{
  __shared__ __align__(16) u16 lds_a[64 * 72];    // y tokens
  __shared__ __align__(16) u16 lds_b[128 * 72];   // Wp channels
  int n0 = blockIdx.x * 128;
  int m0 = blockIdx.y * 64;
  int tid = threadIdx.x;
  int lane = tid & 63, wv_ = tid >> 6;
  int wm = wv_ & 1, wn = wv_ >> 1;
  int mcol = lane & 15, quad = lane >> 4;
  int chunk = tid & 7, rbase = tid >> 3;

  f32x4 acc[2][4] = {};

  for (int k0 = 0; k0 < KDIM; k0 += 64) {
    __syncthreads();
#pragma unroll
    for (int r = 0; r < 2; ++r) {
      int row = rbase + r * 32;
      *(uint4*)&lds_a[row * 72 + chunk * 8] =
          *(const uint4*)&yb[(size_t)(m0 + row) * KDIM + k0 + chunk * 8];
    }
#pragma unroll
    for (int r = 0; r < 4; ++r) {
      int row = rbase + r * 32;
      *(uint4*)&lds_b[row * 72 + chunk * 8] =
          *(const uint4*)&wpb[(size_t)(n0 + row) * KDIM + k0 + chunk * 8];
    }
    __syncthreads();
#pragma unroll
    for (int kc = 0; kc < 2; ++kc) {
      bf16x8 af[2], bfr[4];
#pragma unroll
      for (int i = 0; i < 2; i++)
        af[i] = *(const bf16x8*)&lds_a[(wm * 32 + i * 16 + mcol) * 72 + kc * 32 + quad * 8];
#pragma unroll
      for (int j = 0; j < 4; j++)
        bfr[j] = *(const bf16x8*)&lds_b[(wn * 64 + j * 16 + mcol) * 72 + kc * 32 + quad * 8];
#pragma unroll
      for (int i = 0; i < 2; i++)
#pragma unroll
        for (int j = 0; j < 4; j++)
          acc[i][j] = __builtin_amdgcn_mfma_f32_16x16x32_bf16(bfr[j], af[i], acc[i][j], 0, 0, 0);
    }
  }

#pragma unroll
  for (int i = 0; i < 2; i++) {
    int token = m0 + wm * 32 + i * 16 + mcol;
#pragma unroll
    for (int j = 0; j < 4; j++) {
      int ch0 = n0 + wn * 64 + j * 16 + quad * 4;
      float4 bb4 = *(const float4*)&bp[ch0];
      float4 o4;
      o4.x = acc[i][j][0] + bb4.x;
      o4.y = acc[i][j][1] + bb4.y;
      o4.z = acc[i][j][2] + bb4.z;
      o4.w = acc[i][j][3] + bb4.w;
      *(float4*)&out[(size_t)token * CC + ch0] = o4;
    }
  }
}

extern "C" void kernel_launch(void* const* d_in, const int* in_sizes, int n_in,
                              void* d_out, int out_size, void* d_ws, size_t ws_size,
                              hipStream_t stream) {
  const float* x  = (const float*)d_in[0];
  const float* Wk = (const float*)d_in[1];
  const float* bk = (const float*)d_in[2];
  const float* Wq = (const float*)d_in[3];
  const float* bq = (const float*)d_in[4];
  const float* Wv = (const float*)d_in[5];
  const float* bv = (const float*)d_in[6];
  const float* Wp = (const float*)d_in[7];
  const float* bp = (const float*)d_in[8];
  float* out = (float*)d_out;

  char* ws = (char*)d_ws;
  size_t off = 0;
  auto alloc = [&](size_t bytes) {
    void* p = ws + off;
    off += (bytes + 255) & ~(size_t)255;
    return p;
  };
  const size_t NX = (size_t)2 * TT * CC;
  const size_t NW = (size_t)CC * CC;
  u16* xb  = (u16*)alloc(NX * 2);
  u16* wqb = (u16*)alloc(NW * 2);
  u16* wkb = (u16*)alloc(NW * 2);
  u16* wvb = (u16*)alloc(NW * 2);
  u16* wpb = (u16*)alloc(NW * 2);
  u16* qws = (u16*)alloc(NX * 2);
  u16* kws = (u16*)alloc(NX * 2);
  u16* vgw = (u16*)alloc(NX * 2);
  u16* yws = (u16*)alloc(NX * 2);

  int nx4 = (int)(NX / 4), nw4 = (int)(NW / 4);
  convall<<<dim3((nx4 + 255) / 256, 5), 256, 0, stream>>>(
      x, Wq, Wk, Wv, Wp, xb, wqb, wkb, wvb, wpb, nx4, nw4);

  gemm_qkv<<<dim3(6, 40, 3), 256, 0, stream>>>(xb, wqb, wkb, wvb, bq, bk, bv,
                                               qws, kws, vgw);
  attn<<<dim3(960), 128, 0, stream>>>(qws, kws, vgw, yws);
  gemm_out<<<dim3(6, 80), 256, 0, stream>>>(yws, wpb, bp, out);
}